// Round 1
// baseline (801.628 us; speedup 1.0000x reference)
//
#include <hip/hip_runtime.h>

// VolumeRotation: B=8, C=16, S=64.
// out[b,c,d,h,w] = trilinear sample of vol[b,c] at R^T @ base(d,h,w),
// padding_mode='zeros', align_corners=False.

#define S 64
#define CCH 16
#define BB 8
#define SP (S * S * S)

__global__ __launch_bounds__(256) void vol_rot_kernel(
    const float* __restrict__ vol,   // [B, C, S, S, S]
    const float* __restrict__ rot,   // [B, 3, 3]
    float* __restrict__ out)         // [B, C, S, S, S]
{
    const int tid = blockIdx.x * blockDim.x + threadIdx.x;
    if (tid >= BB * SP) return;

    const int w = tid & (S - 1);
    const int h = (tid >> 6) & (S - 1);
    const int d = (tid >> 12) & (S - 1);
    const int b = tid >> 18;

    // base coords in [-1,1], linspace over 64 points
    const float scale = 2.0f / (S - 1);
    const float xb = -1.0f + w * scale;
    const float yb = -1.0f + h * scale;
    const float zb = -1.0f + d * scale;

    // R row-major [3][3]; grid_i = sum_j R[j][i] * base_j  (R^T @ base)
    const float* R = rot + b * 9;   // wave-uniform -> scalar broadcast loads
    const float gx = R[0] * xb + R[3] * yb + R[6] * zb;
    const float gy = R[1] * xb + R[4] * yb + R[7] * zb;
    const float gz = R[2] * xb + R[5] * yb + R[8] * zb;

    // unnormalize (align_corners=False): x = (gx+1)*W/2 - 0.5
    const float x = (gx + 1.0f) * (0.5f * S) - 0.5f;
    const float y = (gy + 1.0f) * (0.5f * S) - 0.5f;
    const float z = (gz + 1.0f) * (0.5f * S) - 0.5f;

    const float x0f = floorf(x), y0f = floorf(y), z0f = floorf(z);
    const float tx = x - x0f, ty = y - y0f, tz = z - z0f;
    const int x0 = (int)x0f, y0 = (int)y0f, z0 = (int)z0f;

    int   offs[8];
    float wts[8];
#pragma unroll
    for (int k = 0; k < 8; ++k) {
        const int dx = k & 1, dy = (k >> 1) & 1, dz = (k >> 2) & 1;
        const int xi = x0 + dx, yi = y0 + dy, zi = z0 + dz;
        const bool valid = (xi >= 0) & (xi < S) & (yi >= 0) & (yi < S)
                         & (zi >= 0) & (zi < S);
        const int xc = min(max(xi, 0), S - 1);
        const int yc = min(max(yi, 0), S - 1);
        const int zc = min(max(zi, 0), S - 1);
        offs[k] = (zc * S + yc) * S + xc;
        const float wgt = (dx ? tx : 1.0f - tx)
                        * (dy ? ty : 1.0f - ty)
                        * (dz ? tz : 1.0f - tz);
        wts[k] = valid ? wgt : 0.0f;
    }

    const int spatial = tid & (SP - 1);
    const float* vb = vol + (size_t)b * CCH * SP;
    float*       ob = out + (size_t)b * CCH * SP + spatial;

#pragma unroll 4
    for (int c = 0; c < CCH; ++c) {
        const float* vc = vb + c * SP;
        float acc = 0.0f;
#pragma unroll
        for (int k = 0; k < 8; ++k)
            acc += wts[k] * vc[offs[k]];
        ob[c * SP] = acc;
    }
}

extern "C" void kernel_launch(void* const* d_in, const int* in_sizes, int n_in,
                              void* d_out, int out_size, void* d_ws, size_t ws_size,
                              hipStream_t stream) {
    const float* vol = (const float*)d_in[0];
    const float* rot = (const float*)d_in[1];
    float* out = (float*)d_out;

    const int n_spatial = BB * SP;           // 2,097,152 threads
    const int block = 256;
    const int grid = (n_spatial + block - 1) / block;  // 8192 blocks
    vol_rot_kernel<<<grid, block, 0, stream>>>(vol, rot, out);
}

// Round 2
// 355.675 us; speedup vs baseline: 2.2538x; 2.2538x over previous
//
#include <hip/hip_runtime.h>

// VolumeRotation via LDS tiling: B=8, C=16, S=64.
// Each block handles a 16x8x8 output tile for one batch. The rotated
// bounding region of the tile (provably <= 8000 floats incl. +3/axis slack)
// is staged into LDS per channel with ghost zeros outside the volume, then
// each point does 8 LDS reads (4x ds_read2) + trilinear weights.

#define S 64
#define SP (S * S * S)
#define CCH 16
#define BB 8

#define TW 16
#define TH 8
#define TD 8
#define NT 512           // threads per block
#define PPT 2            // points per thread (1024 points / 512 threads)
#define CAP 8192         // LDS floats capacity (worst-case region <= 8000)
#define MAXIT 16         // CAP / NT staging iterations

__global__ __launch_bounds__(NT, 4) void vol_rot_tiled(
    const float* __restrict__ vol,   // [B, C, S, S, S]
    const float* __restrict__ rot,   // [B, 3, 3]
    float* __restrict__ out)         // [B, C, S, S, S]
{
    __shared__ float smem[CAP + 2];

    const int tid = threadIdx.x;
    const int t  = blockIdx.x & 255;
    const int b  = blockIdx.x >> 8;
    const int w0 = (t & 3) * TW;
    const int h0 = ((t >> 2) & 7) * TH;
    const int d0 = (t >> 5) * TD;

    const float* R = rot + b * 9;    // wave-uniform -> scalar loads
    const float R00 = R[0], R01 = R[1], R02 = R[2];
    const float R10 = R[3], R11 = R[4], R12 = R[5];
    const float R20 = R[6], R21 = R[7], R22 = R[8];

    const float st = 2.0f / 63.0f;

    // ---- bounding box of the tile's sample positions (affine -> corners) ----
    float xmn = 1e30f, xmx = -1e30f;
    float ymn = 1e30f, ymx = -1e30f;
    float zmn = 1e30f, zmx = -1e30f;
#pragma unroll
    for (int k = 0; k < 8; ++k) {
        const float xb = -1.0f + (float)(w0 + ((k & 1) ? (TW - 1) : 0)) * st;
        const float yb = -1.0f + (float)(h0 + ((k & 2) ? (TH - 1) : 0)) * st;
        const float zb = -1.0f + (float)(d0 + ((k & 4) ? (TD - 1) : 0)) * st;
        const float gx = R00 * xb + R10 * yb + R20 * zb;
        const float gy = R01 * xb + R11 * yb + R21 * zb;
        const float gz = R02 * xb + R12 * yb + R22 * zb;
        const float vx = (gx + 1.0f) * 32.0f - 0.5f;
        const float vy = (gy + 1.0f) * 32.0f - 0.5f;
        const float vz = (gz + 1.0f) * 32.0f - 0.5f;
        xmn = fminf(xmn, vx); xmx = fmaxf(xmx, vx);
        ymn = fminf(ymn, vy); ymx = fmaxf(ymx, vy);
        zmn = fminf(zmn, vz); zmx = fmaxf(zmx, vz);
    }
    const int rx0 = (int)floorf(xmn);
    const int ry0 = (int)floorf(ymn);
    const int rz0 = (int)floorf(zmn);
    int ex = (int)floorf(xmx) + 2 - rx0;   // region extents (>=2, <=21)
    int ey = (int)floorf(ymx) + 2 - ry0;
    int ez = (int)floorf(zmx) + 2 - rz0;
    if (ex * ey * ez > CAP) ez = CAP / (ex * ey);   // safety (unreachable)

    const int plane = ex * ey;
    const float invp = 1.0f / (float)plane;
    const float inve = 1.0f / (float)ex;

    // ---- staging address precompute (shared across all 16 channels) ----
    int voff[MAXIT];        // byte offset into one channel's volume (clamped)
    unsigned mask = 0;      // bit i: coordinate inside volume
#pragma unroll
    for (int i = 0; i < MAXIT; ++i) {
        const int r  = tid + i * NT;
        const int rz = (int)(((float)r + 0.5f) * invp);
        const int rm = r - rz * plane;
        const int ry = (int)(((float)rm + 0.5f) * inve);
        const int rx = rm - ry * ex;
        const int gx = rx0 + rx, gy = ry0 + ry, gz = rz0 + rz;
        const bool valid = ((unsigned)gx < 64u) & ((unsigned)gy < 64u)
                         & ((unsigned)gz < 64u);
        const int gxc = min(max(gx, 0), 63);
        const int gyc = min(max(gy, 0), 63);
        const int gzc = min(max(gz, 0), 63);
        voff[i] = (((((gzc << 6) + gyc) << 6) + gxc) << 2);
        mask |= ((unsigned)valid) << i;
    }

    // ---- per-point state (shared across channels) ----
    int   obase[PPT];       // LDS byte offset of (z0,y0,x0) corner
    int   ospat[PPT];       // output spatial index
    float wgt[PPT][8];      // trilinear weights, k = dz*4+dy*2+dx
#pragma unroll
    for (int p = 0; p < PPT; ++p) {
        const int idx = tid + p * NT;
        const int pw = idx & 15, ph = (idx >> 4) & 7, pd = idx >> 7;
        const float xb = -1.0f + (float)(w0 + pw) * st;
        const float yb = -1.0f + (float)(h0 + ph) * st;
        const float zb = -1.0f + (float)(d0 + pd) * st;
        const float gx = R00 * xb + R10 * yb + R20 * zb;
        const float gy = R01 * xb + R11 * yb + R21 * zb;
        const float gz = R02 * xb + R12 * yb + R22 * zb;
        const float vx = (gx + 1.0f) * 32.0f - 0.5f;
        const float vy = (gy + 1.0f) * 32.0f - 0.5f;
        const float vz = (gz + 1.0f) * 32.0f - 0.5f;
        const float fx = floorf(vx), fy = floorf(vy), fz = floorf(vz);
        const float tx = vx - fx, ty = vy - fy, tz = vz - fz;
        int lx = (int)fx - rx0, ly = (int)fy - ry0, lz = (int)fz - rz0;
        lx = min(max(lx, 0), ex - 2);   // clamp only engages when weight==0
        ly = min(max(ly, 0), ey - 2);   // or ~1e-5 (fp rounding at edges)
        lz = min(max(lz, 0), ez - 2);
        obase[p] = ((lz * ey + ly) * ex + lx) * 4;
        ospat[p] = ((d0 + pd) * 64 + (h0 + ph)) * 64 + (w0 + pw);
        const float ux = 1.0f - tx, uy = 1.0f - ty, uz = 1.0f - tz;
        wgt[p][0] = uz * uy * ux; wgt[p][1] = uz * uy * tx;
        wgt[p][2] = uz * ty * ux; wgt[p][3] = uz * ty * tx;
        wgt[p][4] = tz * uy * ux; wgt[p][5] = tz * uy * tx;
        wgt[p][6] = tz * ty * ux; wgt[p][7] = tz * ty * tx;
    }

    // ---- channel loop: stage region -> LDS, then sample ----
    const char* smemb = (const char*)smem;
    const int dy4 = ex * 4;
    const int dz4 = plane * 4;
    const float* volb = vol + (size_t)b * CCH * SP;
    float*       outb = out + (size_t)b * CCH * SP;

    // prefetch channel 0
    float vals[MAXIT];
    {
        const char* vc = (const char*)volb;
#pragma unroll
        for (int i = 0; i < MAXIT; ++i)
            vals[i] = *(const float*)(vc + voff[i]);
    }

    for (int c = 0; c < CCH; ++c) {
        __syncthreads();    // previous channel's sampling done
#pragma unroll
        for (int i = 0; i < MAXIT; ++i) {
            const float v = ((mask >> i) & 1u) ? vals[i] : 0.0f;
            smem[tid + i * NT] = v;
        }
        __syncthreads();    // region visible

        // prefetch next channel's region (overlaps with sampling below)
        if (c + 1 < CCH) {
            const char* vc = (const char*)(volb + (c + 1) * SP);
#pragma unroll
            for (int i = 0; i < MAXIT; ++i)
                vals[i] = *(const float*)(vc + voff[i]);
        }

#pragma unroll
        for (int p = 0; p < PPT; ++p) {
            const char* pb = smemb + obase[p];
            const float v000 = *(const float*)(pb);
            const float v001 = *(const float*)(pb + 4);
            const float v010 = *(const float*)(pb + dy4);
            const float v011 = *(const float*)(pb + dy4 + 4);
            const float v100 = *(const float*)(pb + dz4);
            const float v101 = *(const float*)(pb + dz4 + 4);
            const float v110 = *(const float*)(pb + dz4 + dy4);
            const float v111 = *(const float*)(pb + dz4 + dy4 + 4);
            const float acc = wgt[p][0] * v000 + wgt[p][1] * v001
                            + wgt[p][2] * v010 + wgt[p][3] * v011
                            + wgt[p][4] * v100 + wgt[p][5] * v101
                            + wgt[p][6] * v110 + wgt[p][7] * v111;
            outb[c * SP + ospat[p]] = acc;
        }
    }
}

extern "C" void kernel_launch(void* const* d_in, const int* in_sizes, int n_in,
                              void* d_out, int out_size, void* d_ws, size_t ws_size,
                              hipStream_t stream) {
    const float* vol = (const float*)d_in[0];
    const float* rot = (const float*)d_in[1];
    float* out = (float*)d_out;

    // 8 batches x (4 x 8 x 8) tiles = 2048 blocks
    vol_rot_tiled<<<dim3(BB * 256), dim3(NT), 0, stream>>>(vol, rot, out);
}